// Round 9
// baseline (206.966 us; speedup 1.0000x reference)
//
#include <hip/hip_runtime.h>
#include <hip/hip_bf16.h>

#define NEG_SLOPE 0.2f
#define EPSF 1e-16f

typedef __attribute__((ext_vector_type(8))) short short8;     // 8 bf16 = 4 VGPR
typedef __attribute__((ext_vector_type(4))) float floatx4;    // MFMA acc

__device__ __forceinline__ float bf2f(unsigned short u) {
  union { unsigned int i; float f; } v; v.i = ((unsigned int)u) << 16; return v.f;
}
__device__ __forceinline__ unsigned short f2bf(float f) {
  union { float f; unsigned int i; } v; v.f = f;
  unsigned int r = v.i + 0x7fffu + ((v.i >> 16) & 1u);  // RNE
  return (unsigned short)(r >> 16);
}

// ---------------- merged prep: zero cursor (blocks<zb) | detect+pack (blocks>=zb) -------
__global__ __launch_bounds__(256) void prep_k(const unsigned short* __restrict__ xw,
                                              const void* __restrict__ w,
                                              const void* __restrict__ att,
                                              const void* __restrict__ bias,
                                              int* __restrict__ flag,
                                              int* __restrict__ cursor,
                                              int* __restrict__ ovf_cnt,
                                              unsigned short* __restrict__ bpack,
                                              unsigned short* __restrict__ wpack,
                                              float* __restrict__ bias_f,
                                              int n, int zb) {
  int b = blockIdx.x;
  if (b < zb) {
    int i = b * 256 + threadIdx.x;
    if (i < n) cursor[i] = 0;
    if (i == 0) *ovf_cnt = 0;
    return;
  }
  // inline per-block dtype detect (redundant but removes cross-kernel dependency)
  __shared__ int cnt;
  if (threadIdx.x == 0) cnt = 0;
  __syncthreads();
  int local = 0;
  for (int k2 = 0; k2 < 16; k2++) {
    unsigned short u = xw[(threadIdx.x * 16 + k2) << 1];
    int ex = (u >> 7) & 0xFF;
    if (ex >= 0x90 || ex <= 0x40) local++;
  }
  atomicAdd(&cnt, local);
  __syncthreads();
  int f32 = (cnt > 256) ? 1 : 0;
  int pb = b - zb;
  if (pb == 0 && threadIdx.x == 0) *flag = f32;  // publish for gemmfill/agg
  if (pb < 128) {
    int i = pb * 256 + threadIdx.x;  // 0..32767
    int j = i & 7, lane = (i >> 3) & 63, nt = (i >> 9) & 7, kb = i >> 12;
    int f = (kb << 5) + ((lane >> 4) << 3) + j;
    int col = (nt << 4) + (lane & 15);
    int src = ((col >> 5) << 13) + (f << 5) + (col & 31);
    float v = f32 ? ((const float*)w)[src] : bf2f(((const unsigned short*)w)[src]);
    bpack[i] = f2bf(v);
  } else if (pb < 144) {
    int i = (pb - 128) * 256 + threadIdx.x;  // 0..4095
    int j = i & 7, lane = (i >> 3) & 63, kb = i >> 9;
    int quad = lane >> 4, m16 = lane & 15;
    int f = (kb << 5) + (quad << 3) + j;
    float v = 0.f;
    if (m16 < 8) {
      int hd = m16 & 3;
      int db = (m16 >= 4) ? 32 : 0;
      int wbase = (hd << 13) + (f << 5);
      int abase = (hd << 6) + db;
      float acc = 0.f;
      for (int c = 0; c < 32; c++) {
        float wv = f32 ? ((const float*)w)[wbase + c] : bf2f(((const unsigned short*)w)[wbase + c]);
        float av = f32 ? ((const float*)att)[abase + c] : bf2f(((const unsigned short*)att)[abase + c]);
        acc = fmaf(wv, av, acc);
      }
      v = acc;
    }
    wpack[i] = f2bf(v);
  } else {
    int i = threadIdx.x;
    if (i < 128) bias_f[i] = f32 ? ((const float*)bias)[i] : bf2f(((const unsigned short*)bias)[i]);
  }
}

// ---------------- fused: bf16-MFMA gemm+attlogits (blocks < gb) | XCD-sharded fill ------
__global__ __launch_bounds__(256) void gemmfill_k(const void* __restrict__ xv,
                                                  const int* __restrict__ flag,
                                                  const unsigned short* __restrict__ bpack,
                                                  const unsigned short* __restrict__ wpack,
                                                  unsigned short* __restrict__ h,
                                                  float* __restrict__ a_srcp,
                                                  float* __restrict__ a_dstp,
                                                  const int* __restrict__ ei,
                                                  int* __restrict__ cursor,
                                                  int* __restrict__ ed,
                                                  int2* __restrict__ ovf,
                                                  int* __restrict__ ovf_cnt,
                                                  int n, int e, int gb, int fb) {
  int b = blockIdx.x;
  if (b < gb) {
    int t = threadIdx.x;
    int wave = t >> 6, l = t & 63;
    int quad = l >> 4, m16 = l & 15;
    long n0 = (long)b * 128 + wave * 32;
    int isf32 = *flag;

    floatx4 acc[2][8];
    floatx4 acca[2];
#pragma unroll
    for (int mt = 0; mt < 2; mt++) {
      acca[mt] = (floatx4){0.f, 0.f, 0.f, 0.f};
#pragma unroll
      for (int nt = 0; nt < 8; nt++) acc[mt][nt] = (floatx4){0.f, 0.f, 0.f, 0.f};
    }

    for (int kb = 0; kb < 8; kb++) {
      short8 afr[2];
#pragma unroll
      for (int mt = 0; mt < 2; mt++) {
        long row = n0 + mt * 16 + m16;
        if (row >= n) row = n - 1;  // clamp; result discarded at store
        if (isf32) {
          const float* xp = (const float*)xv + (row << 8) + (kb << 5) + (quad << 3);
          float4 u0 = *(const float4*)xp;
          float4 u1 = *(const float4*)(xp + 4);
          short8 a;
          a[0] = (short)f2bf(u0.x); a[1] = (short)f2bf(u0.y);
          a[2] = (short)f2bf(u0.z); a[3] = (short)f2bf(u0.w);
          a[4] = (short)f2bf(u1.x); a[5] = (short)f2bf(u1.y);
          a[6] = (short)f2bf(u1.z); a[7] = (short)f2bf(u1.w);
          afr[mt] = a;
        } else {
          afr[mt] = *(const short8*)((const unsigned short*)xv + (row << 8) + (kb << 5) + (quad << 3));
        }
      }
      short8 wfr = *(const short8*)(wpack + (((kb << 6) + l) << 3));
      acca[0] = __builtin_amdgcn_mfma_f32_16x16x32_bf16(afr[0], wfr, acca[0], 0, 0, 0);
      acca[1] = __builtin_amdgcn_mfma_f32_16x16x32_bf16(afr[1], wfr, acca[1], 0, 0, 0);
#pragma unroll
      for (int nt = 0; nt < 8; nt++) {
        short8 bfr = *(const short8*)(bpack + (((kb << 3) + nt) << 9) + (l << 3));
        acc[0][nt] = __builtin_amdgcn_mfma_f32_16x16x32_bf16(afr[0], bfr, acc[0][nt], 0, 0, 0);
        acc[1][nt] = __builtin_amdgcn_mfma_f32_16x16x32_bf16(afr[1], bfr, acc[1][nt], 0, 0, 0);
      }
    }
    // epilogue: C/D layout col = l&15, row = quad*4 + r
#pragma unroll
    for (int mt = 0; mt < 2; mt++)
#pragma unroll
      for (int r = 0; r < 4; r++) {
        long row = n0 + mt * 16 + quad * 4 + r;
        if (row < n) {
#pragma unroll
          for (int nt = 0; nt < 8; nt++)
            h[(row << 7) + (nt << 4) + m16] = f2bf(acc[mt][nt][r]);
          if (m16 < 8) {
            float val = acca[mt][r];
            int hd = m16 & 3;
            if (m16 < 4) a_srcp[(row << 2) + hd] = val;
            else         a_dstp[(row << 2) + hd] = val;
          }
        }
      }
  } else {
    // XCD-sharded scatter: shard = (blockIdx%8)>>1 (XCD pair), dst-range L2-resident.
    int fbi = b - gb;
    int k = b & 7;
    int shard = k >> 1;
    int sub = ((fbi >> 3) << 1) | (k & 1);   // 0..(fb>>2)-1, unique per shard
    int nsub = fb >> 2;
    int ns = (n + 3) >> 2;
    unsigned lo = (unsigned)(shard * ns);
    unsigned hi = (unsigned)min(n, (shard + 1) * ns);
    int nchunks = (e + 255) >> 8;
    for (int c = sub; c < nchunks; c += nsub) {
      int i = (c << 8) + threadIdx.x;
      if (i < e) {
        unsigned d = (unsigned)ei[e + i];
        if (d >= lo && d < hi) {
          int s = ei[i];
          if ((unsigned)s >= (unsigned)n) s = 0;
          int c2 = atomicAdd(&cursor[d], 1);
          if (c2 < 32) {
            ed[((int)d << 5) + c2] = s;
          } else {
            int kk = atomicAdd(ovf_cnt, 1);
            if (kk < e) ovf[kk] = make_int2((int)d, s);
          }
        }
      }
    }
  }
}

// ---------------- wave-per-node online-softmax aggregate; 16B/lane gather ----------------
__global__ __launch_bounds__(512) void agg_k(const unsigned short* __restrict__ hfeat,
                                             const int* __restrict__ cursor,
                                             const int* __restrict__ ed,
                                             const int2* __restrict__ ovf,
                                             const int* __restrict__ ovf_cnt,
                                             const float* __restrict__ a_src,
                                             const float* __restrict__ a_dst,
                                             const float* __restrict__ bias_f,
                                             const int* __restrict__ flag,
                                             void* __restrict__ outv, int n, int e) {
  int wave = threadIdx.x >> 6;
  int l = threadIdx.x & 63;
  int node = (blockIdx.x << 3) + wave;
  if (node >= n) return;
  int total = cursor[node];
  int cnt0 = min(total, 32);
  int hq = l & 3;          // weight-phase head (slot l>>2)
  int c8 = l & 15;         // gather col group
  int hg = c8 >> 2;        // gather-phase head
  int q = l >> 4;          // quarter
  float4 ad4 = *(const float4*)&a_dst[node << 2];
  float adq = (hq == 0) ? ad4.x : (hq == 1) ? ad4.y : (hq == 2) ? ad4.z : ad4.w;

  float m_run = -3.0e38f;
  float swacc = 0.f;
  float acc[8];
#pragma unroll
  for (int k = 0; k < 8; k++) acc[k] = 0.f;

  // ---- in-slot chunks (<=2) ----
  for (int c0 = 0; c0 < cnt0; c0 += 16) {
    int cnt = min(16, cnt0 - c0);
    int srcv = 0;
    if (l < 16 && (c0 + l) < cnt0) srcv = ed[(node << 5) + c0 + l];
    int myslot = l >> 2;
    int ss = __shfl(srcv, myslot, 64);
    float z = -3.0e38f;
    if (myslot < cnt) {
      float zz = a_src[(ss << 2) + hq] + adq;
      z = zz > 0.f ? zz : NEG_SLOPE * zz;
    }
    float cm = z;
    cm = fmaxf(cm, __shfl_xor(cm, 4, 64));
    cm = fmaxf(cm, __shfl_xor(cm, 8, 64));
    cm = fmaxf(cm, __shfl_xor(cm, 16, 64));
    cm = fmaxf(cm, __shfl_xor(cm, 32, 64));
    float m_new = fmaxf(m_run, cm);
    float resc_q = __expf(m_run - m_new);
    m_run = m_new;
    float wexp = (myslot < cnt) ? __expf(z - m_new) : 0.f;
    swacc = swacc * resc_q + wexp;
    float resc_h = __shfl(resc_q, hg, 64);
#pragma unroll
    for (int k = 0; k < 8; k++) acc[k] *= resc_h;
#pragma unroll
    for (int js = 0; js < 4; js++) {
      if ((js << 2) < cnt) {
        int eidx = (js << 2) + q;
        float sw = __shfl(wexp, (eidx << 2) | hg, 64);
        int sj = __shfl(srcv, eidx, 64);
        uint4 hv = *(const uint4*)(hfeat + (((size_t)sj) << 7) + (c8 << 3));
        unsigned uu[4] = {hv.x, hv.y, hv.z, hv.w};
#pragma unroll
        for (int k2 = 0; k2 < 4; k2++) {
          acc[2 * k2]     = fmaf(sw, bf2f((unsigned short)(uu[k2] & 0xffffu)), acc[2 * k2]);
          acc[2 * k2 + 1] = fmaf(sw, bf2f((unsigned short)(uu[k2] >> 16)), acc[2 * k2 + 1]);
        }
      }
    }
  }

  // ---- overflow scan (rare: only nodes with degree > 32) ----
  if (total > 32) {
    int K = *ovf_cnt;
    if (K > e) K = e;
    for (int c0 = 0; c0 < K; c0 += 16) {
      int sv = 0, dv = -1;
      if (l < 16 && (c0 + l) < K) { int2 pr = ovf[c0 + l]; dv = pr.x; sv = pr.y; }
      int myslot = l >> 2;
      int dmy = __shfl(dv, myslot, 64);
      int smy = __shfl(sv, myslot, 64);
      bool valid = (dmy == node);
      float z = -3.0e38f;
      if (valid) {
        float zz = a_src[(smy << 2) + hq] + adq;
        z = zz > 0.f ? zz : NEG_SLOPE * zz;
      }
      float cm = z;
      cm = fmaxf(cm, __shfl_xor(cm, 4, 64));
      cm = fmaxf(cm, __shfl_xor(cm, 8, 64));
      cm = fmaxf(cm, __shfl_xor(cm, 16, 64));
      cm = fmaxf(cm, __shfl_xor(cm, 32, 64));
      float m_new = fmaxf(m_run, cm);
      float resc_q = __expf(m_run - m_new);
      m_run = m_new;
      float wexp = valid ? __expf(z - m_new) : 0.f;
      swacc = swacc * resc_q + wexp;
      float resc_h = __shfl(resc_q, hg, 64);
#pragma unroll
      for (int k = 0; k < 8; k++) acc[k] *= resc_h;
#pragma unroll
      for (int js = 0; js < 4; js++) {
        int eidx = (js << 2) + q;
        float sw = __shfl(wexp, (eidx << 2) | hg, 64);
        int sj = __shfl(sv, eidx, 64);
        uint4 hv = *(const uint4*)(hfeat + (((size_t)sj) << 7) + (c8 << 3));
        unsigned uu[4] = {hv.x, hv.y, hv.z, hv.w};
#pragma unroll
        for (int k2 = 0; k2 < 4; k2++) {
          acc[2 * k2]     = fmaf(sw, bf2f((unsigned short)(uu[k2] & 0xffffu)), acc[2 * k2]);
          acc[2 * k2 + 1] = fmaf(sw, bf2f((unsigned short)(uu[k2] >> 16)), acc[2 * k2 + 1]);
        }
      }
    }
  }

  // per-head exp-sum over the 16 lanes sharing hq
  for (int m = 4; m < 64; m <<= 1) swacc += __shfl_xor(swacc, m, 64);
  // cross-quarter accumulator reduce
#pragma unroll
  for (int k = 0; k < 8; k++) {
    acc[k] += __shfl_xor(acc[k], 16, 64);
    acc[k] += __shfl_xor(acc[k], 32, 64);
  }
  float sumv = __shfl(swacc, hg, 64);
  float rs = 1.f / (sumv + EPSF);
  if (l < 16) {
    float o[8];
#pragma unroll
    for (int k = 0; k < 8; k++) o[k] = fmaf(acc[k], rs, bias_f[(c8 << 3) + k]);
    size_t base = (((size_t)node) << 7) + (c8 << 3);
    if (*flag) {
      *(float4*)((float*)outv + base)     = make_float4(o[0], o[1], o[2], o[3]);
      *(float4*)((float*)outv + base + 4) = make_float4(o[4], o[5], o[6], o[7]);
    } else {
      uint4 pk;
      pk.x = (unsigned)f2bf(o[0]) | ((unsigned)f2bf(o[1]) << 16);
      pk.y = (unsigned)f2bf(o[2]) | ((unsigned)f2bf(o[3]) << 16);
      pk.z = (unsigned)f2bf(o[4]) | ((unsigned)f2bf(o[5]) << 16);
      pk.w = (unsigned)f2bf(o[6]) | ((unsigned)f2bf(o[7]) << 16);
      *(uint4*)((unsigned short*)outv + base) = pk;
    }
  }
}

extern "C" void kernel_launch(void* const* d_in, const int* in_sizes, int n_in,
                              void* d_out, int out_size, void* d_ws, size_t ws_size,
                              hipStream_t stream) {
  const void* x    = d_in[0];
  const int*  ei   = (const int*)d_in[1];
  const void* w    = d_in[2];
  const void* att  = d_in[3];
  const void* bias = d_in[4];

  const int n = in_sizes[0] / 256;
  const int e = in_sizes[1] / 2;
  const int zb = (n + 255) / 256;            // cursor-zero blocks
  const int gb = (n + 127) / 128;            // gemm blocks
  const int fb = 2048;                       // fill blocks (multiple of 8)

  char* p = (char*)d_ws;
  size_t off = 0;
  auto carve = [&](size_t bytes) -> void* {
    void* r = p + off;
    off = (off + bytes + 255) & ~(size_t)255;
    return r;
  };
  int*      flag    = (int*)carve(sizeof(int));
  int*      ovf_cnt = (int*)carve(sizeof(int));
  float*    bias_f  = (float*)carve(128 * 4);
  unsigned short* h = (unsigned short*)carve((size_t)n * 128 * 2);   // 12.8 MB
  float*    a_src   = (float*)carve((size_t)n * 4 * 4);
  float*    a_dst   = (float*)carve((size_t)n * 4 * 4);
  int*      cursor  = (int*)carve((size_t)n * 4);
  int*      ed      = (int*)carve((size_t)n * 32 * 4);               // 6.4 MB
  int2*     ovf     = (int2*)carve((size_t)e * 8);                   // 6.4 MB
  unsigned short* bpack = (unsigned short*)carve((size_t)256 * 128 * 2);  // 64 KB
  unsigned short* wpack = (unsigned short*)carve((size_t)8 * 64 * 8 * 2); // 8 KB
  (void)ws_size;

  prep_k<<<zb + 145, 256, 0, stream>>>((const unsigned short*)x, w, att, bias,
                                       flag, cursor, ovf_cnt, bpack, wpack, bias_f,
                                       n, zb);
  gemmfill_k<<<gb + fb, 256, 0, stream>>>(x, flag, bpack, wpack, h, a_src, a_dst,
                                          ei, cursor, ed, ovf, ovf_cnt, n, e, gb, fb);
  agg_k<<<(n + 7) / 8, 512, 0, stream>>>(h, cursor, ed, ovf, ovf_cnt, a_src, a_dst,
                                         bias_f, flag, d_out, n, e);
}

// Round 10
// 189.325 us; speedup vs baseline: 1.0932x; 1.0932x over previous
//
#include <hip/hip_runtime.h>
#include <hip/hip_bf16.h>

#define NEG_SLOPE 0.2f
#define EPSF 1e-16f

typedef __attribute__((ext_vector_type(8))) short short8;     // 8 bf16 = 4 VGPR
typedef __attribute__((ext_vector_type(4))) float floatx4;    // MFMA acc

__device__ __forceinline__ float bf2f(unsigned short u) {
  union { unsigned int i; float f; } v; v.i = ((unsigned int)u) << 16; return v.f;
}
__device__ __forceinline__ unsigned short f2bf(float f) {
  union { float f; unsigned int i; } v; v.f = f;
  unsigned int r = v.i + 0x7fffu + ((v.i >> 16) & 1u);  // RNE
  return (unsigned short)(r >> 16);
}

// ---------------- merged prep: zero cursor (blocks<zb) | detect+pack (blocks>=zb) -------
__global__ __launch_bounds__(256) void prep_k(const unsigned short* __restrict__ xw,
                                              const void* __restrict__ w,
                                              const void* __restrict__ att,
                                              const void* __restrict__ bias,
                                              int* __restrict__ flag,
                                              int* __restrict__ cursor,
                                              int* __restrict__ ovf_cnt,
                                              unsigned short* __restrict__ bpack,
                                              unsigned short* __restrict__ wpack,
                                              float* __restrict__ bias_f,
                                              int n, int zb) {
  int b = blockIdx.x;
  if (b < zb) {
    int i = b * 256 + threadIdx.x;
    if (i < n) cursor[i] = 0;
    if (i == 0) *ovf_cnt = 0;
    return;
  }
  __shared__ int cnt;
  if (threadIdx.x == 0) cnt = 0;
  __syncthreads();
  int local = 0;
  for (int k2 = 0; k2 < 16; k2++) {
    unsigned short u = xw[(threadIdx.x * 16 + k2) << 1];
    int ex = (u >> 7) & 0xFF;
    if (ex >= 0x90 || ex <= 0x40) local++;
  }
  atomicAdd(&cnt, local);
  __syncthreads();
  int f32 = (cnt > 256) ? 1 : 0;
  int pb = b - zb;
  if (pb == 0 && threadIdx.x == 0) *flag = f32;
  if (pb < 128) {
    int i = pb * 256 + threadIdx.x;  // 0..32767
    int j = i & 7, lane = (i >> 3) & 63, nt = (i >> 9) & 7, kb = i >> 12;
    int f = (kb << 5) + ((lane >> 4) << 3) + j;
    int col = (nt << 4) + (lane & 15);
    int src = ((col >> 5) << 13) + (f << 5) + (col & 31);
    float v = f32 ? ((const float*)w)[src] : bf2f(((const unsigned short*)w)[src]);
    bpack[i] = f2bf(v);
  } else if (pb < 144) {
    int i = (pb - 128) * 256 + threadIdx.x;  // 0..4095
    int j = i & 7, lane = (i >> 3) & 63, kb = i >> 9;
    int quad = lane >> 4, m16 = lane & 15;
    int f = (kb << 5) + (quad << 3) + j;
    float v = 0.f;
    if (m16 < 8) {
      int hd = m16 & 3;
      int db = (m16 >= 4) ? 32 : 0;
      int wbase = (hd << 13) + (f << 5);
      int abase = (hd << 6) + db;
      float acc = 0.f;
      for (int c = 0; c < 32; c++) {
        float wv = f32 ? ((const float*)w)[wbase + c] : bf2f(((const unsigned short*)w)[wbase + c]);
        float av = f32 ? ((const float*)att)[abase + c] : bf2f(((const unsigned short*)att)[abase + c]);
        acc = fmaf(wv, av, acc);
      }
      v = acc;
    }
    wpack[i] = f2bf(v);
  } else {
    int i = threadIdx.x;
    if (i < 128) bias_f[i] = f32 ? ((const float*)bias)[i] : bf2f(((const unsigned short*)bias)[i]);
  }
}

// ---------------- fused: bf16-MFMA gemm+attlogits (blocks < gb) | XCD-sharded fill ------
__global__ __launch_bounds__(256) void gemmfill_k(const void* __restrict__ xv,
                                                  const int* __restrict__ flag,
                                                  const unsigned short* __restrict__ bpack,
                                                  const unsigned short* __restrict__ wpack,
                                                  unsigned short* __restrict__ h,
                                                  float* __restrict__ a_srcp,
                                                  float* __restrict__ a_dstp,
                                                  const int* __restrict__ ei,
                                                  int* __restrict__ cursor,
                                                  int* __restrict__ ed,
                                                  int2* __restrict__ ovf,
                                                  int* __restrict__ ovf_cnt,
                                                  int n, int e, int gb, int fb) {
  int b = blockIdx.x;
  if (b < gb) {
    int t = threadIdx.x;
    int wave = t >> 6, l = t & 63;
    int quad = l >> 4, m16 = l & 15;
    long n0 = (long)b * 128 + wave * 32;
    int isf32 = *flag;

    floatx4 acc[2][8];
    floatx4 acca[2];
#pragma unroll
    for (int mt = 0; mt < 2; mt++) {
      acca[mt] = (floatx4){0.f, 0.f, 0.f, 0.f};
#pragma unroll
      for (int nt = 0; nt < 8; nt++) acc[mt][nt] = (floatx4){0.f, 0.f, 0.f, 0.f};
    }

    for (int kb = 0; kb < 8; kb++) {
      short8 afr[2];
#pragma unroll
      for (int mt = 0; mt < 2; mt++) {
        long row = n0 + mt * 16 + m16;
        if (row >= n) row = n - 1;  // clamp; result discarded at store
        if (isf32) {
          const float* xp = (const float*)xv + (row << 8) + (kb << 5) + (quad << 3);
          float4 u0 = *(const float4*)xp;
          float4 u1 = *(const float4*)(xp + 4);
          short8 a;
          a[0] = (short)f2bf(u0.x); a[1] = (short)f2bf(u0.y);
          a[2] = (short)f2bf(u0.z); a[3] = (short)f2bf(u0.w);
          a[4] = (short)f2bf(u1.x); a[5] = (short)f2bf(u1.y);
          a[6] = (short)f2bf(u1.z); a[7] = (short)f2bf(u1.w);
          afr[mt] = a;
        } else {
          afr[mt] = *(const short8*)((const unsigned short*)xv + (row << 8) + (kb << 5) + (quad << 3));
        }
      }
      short8 wfr = *(const short8*)(wpack + (((kb << 6) + l) << 3));
      acca[0] = __builtin_amdgcn_mfma_f32_16x16x32_bf16(afr[0], wfr, acca[0], 0, 0, 0);
      acca[1] = __builtin_amdgcn_mfma_f32_16x16x32_bf16(afr[1], wfr, acca[1], 0, 0, 0);
#pragma unroll
      for (int nt = 0; nt < 8; nt++) {
        short8 bfr = *(const short8*)(bpack + (((kb << 3) + nt) << 9) + (l << 3));
        acc[0][nt] = __builtin_amdgcn_mfma_f32_16x16x32_bf16(afr[0], bfr, acc[0][nt], 0, 0, 0);
        acc[1][nt] = __builtin_amdgcn_mfma_f32_16x16x32_bf16(afr[1], bfr, acc[1][nt], 0, 0, 0);
      }
    }
#pragma unroll
    for (int mt = 0; mt < 2; mt++)
#pragma unroll
      for (int r = 0; r < 4; r++) {
        long row = n0 + mt * 16 + quad * 4 + r;
        if (row < n) {
#pragma unroll
          for (int nt = 0; nt < 8; nt++)
            h[(row << 7) + (nt << 4) + m16] = f2bf(acc[mt][nt][r]);
          if (m16 < 8) {
            float val = acca[mt][r];
            int hd = m16 & 3;
            if (m16 < 4) a_srcp[(row << 2) + hd] = val;
            else         a_dstp[(row << 2) + hd] = val;
          }
        }
      }
  } else {
    // XCD-sharded scatter, 2 edges per thread per iteration (independent chains)
    int fbi = b - gb;
    int k = b & 7;
    int shard = k >> 1;
    int sub = ((fbi >> 3) << 1) | (k & 1);
    int nsub = fb >> 2;
    int ns = (n + 3) >> 2;
    unsigned lo = (unsigned)(shard * ns);
    unsigned hi = (unsigned)min(n, (shard + 1) * ns);
    int nchunks = (e + 511) >> 9;
    for (int c = sub; c < nchunks; c += nsub) {
      int i0 = (c << 9) + threadIdx.x;
      int i1 = i0 + 256;
      unsigned d0 = 0xFFFFFFFFu, d1 = 0xFFFFFFFFu;
      int s0 = 0, s1 = 0;
      if (i0 < e) { d0 = (unsigned)ei[e + i0]; s0 = ei[i0]; }
      if (i1 < e) { d1 = (unsigned)ei[e + i1]; s1 = ei[i1]; }
      bool p0 = (d0 >= lo && d0 < hi);
      bool p1 = (d1 >= lo && d1 < hi);
      int c0 = -1, c1 = -1;
      if (p0) { if ((unsigned)s0 >= (unsigned)n) s0 = 0; c0 = atomicAdd(&cursor[d0], 1); }
      if (p1) { if ((unsigned)s1 >= (unsigned)n) s1 = 0; c1 = atomicAdd(&cursor[d1], 1); }
      if (p0) {
        if (c0 < 32) ed[((int)d0 << 5) + c0] = s0;
        else { int kk = atomicAdd(ovf_cnt, 1); if (kk < e) ovf[kk] = make_int2((int)d0, s0); }
      }
      if (p1) {
        if (c1 < 32) ed[((int)d1 << 5) + c1] = s1;
        else { int kk = atomicAdd(ovf_cnt, 1); if (kk < e) ovf[kk] = make_int2((int)d1, s1); }
      }
    }
  }
}

// ---------------- wave-per-node two-phase softmax aggregate; register-staged gather -----
__global__ __launch_bounds__(512) void agg_k(const unsigned short* __restrict__ hfeat,
                                             const int* __restrict__ cursor,
                                             const int* __restrict__ ed,
                                             const int2* __restrict__ ovf,
                                             const int* __restrict__ ovf_cnt,
                                             const float* __restrict__ a_src,
                                             const float* __restrict__ a_dst,
                                             const float* __restrict__ bias_f,
                                             const int* __restrict__ flag,
                                             void* __restrict__ outv, int n, int e) {
  int wave = threadIdx.x >> 6;
  int l = threadIdx.x & 63;
  int node = (blockIdx.x << 3) + wave;
  if (node >= n) return;
  int total = cursor[node];
  int cnt0 = min(total, 32);
  int hq = l & 3;          // weight-phase head (slots l>>2 and 16+(l>>2))
  int c8 = l & 15;         // gather col group
  int hg = c8 >> 2;        // gather-phase head
  int q = l >> 4;          // quarter
  float4 ad4 = *(const float4*)&a_dst[node << 2];
  float adq = (hq == 0) ? ad4.x : (hq == 1) ? ad4.y : (hq == 2) ? ad4.z : ad4.w;

  float m_run = -3.0e38f;
  float swacc = 0.f;
  float acc[8];
#pragma unroll
  for (int k = 0; k < 8; k++) acc[k] = 0.f;

  if (cnt0 > 0) {
    // stage all <=32 src indices: one coalesced 128B read (lanes 0..31)
    int srcv = 0;
    if (l < 32 && l < cnt0) srcv = ed[(node << 5) + l];
    int myslot = l >> 2;
    int ssA = __shfl(srcv, myslot, 64);
    int ssB = __shfl(srcv, myslot + 16, 64);
    // logits (2 per lane)
    float zA = -3.0e38f, zB = -3.0e38f;
    if (myslot < cnt0) {
      float zz = a_src[(ssA << 2) + hq] + adq;
      zA = zz > 0.f ? zz : NEG_SLOPE * zz;
    }
    if (myslot + 16 < cnt0) {
      float zz = a_src[(ssB << 2) + hq] + adq;
      zB = zz > 0.f ? zz : NEG_SLOPE * zz;
    }
    // single true max over all slots (per-head group of 16 lanes)
    float cm = fmaxf(zA, zB);
    cm = fmaxf(cm, __shfl_xor(cm, 4, 64));
    cm = fmaxf(cm, __shfl_xor(cm, 8, 64));
    cm = fmaxf(cm, __shfl_xor(cm, 16, 64));
    cm = fmaxf(cm, __shfl_xor(cm, 32, 64));
    float wexpA = (myslot < cnt0) ? __expf(zA - cm) : 0.f;
    float wexpB = (myslot + 16 < cnt0) ? __expf(zB - cm) : 0.f;
    m_run = cm;
    swacc = wexpA + wexpB;
    // issue ALL h-row gathers back-to-back (up to 8 outstanding 16B loads/lane)
    uint4 hv[8];
    int njs = (cnt0 + 3) >> 2;  // wave-uniform
#pragma unroll
    for (int j = 0; j < 8; j++) {
      if (j < njs) {
        int sj = __shfl(srcv, (j << 2) + q, 64);
        hv[j] = *(const uint4*)(hfeat + (((size_t)sj) << 7) + (c8 << 3));
      }
    }
    // fma from registers
#pragma unroll
    for (int j = 0; j < 8; j++) {
      if (j < njs) {
        int eidx = (j << 2) + q;
        float sw = (j < 4) ? __shfl(wexpA, (eidx << 2) | hg, 64)
                           : __shfl(wexpB, ((eidx - 16) << 2) | hg, 64);
        unsigned uu[4] = {hv[j].x, hv[j].y, hv[j].z, hv[j].w};
#pragma unroll
        for (int k2 = 0; k2 < 4; k2++) {
          acc[2 * k2]     = fmaf(sw, bf2f((unsigned short)(uu[k2] & 0xffffu)), acc[2 * k2]);
          acc[2 * k2 + 1] = fmaf(sw, bf2f((unsigned short)(uu[k2] >> 16)), acc[2 * k2 + 1]);
        }
      }
    }
  }

  // ---- overflow scan (rare: only nodes with degree > 32), online merge ----
  if (total > 32) {
    int K = *ovf_cnt;
    if (K > e) K = e;
    for (int c0 = 0; c0 < K; c0 += 16) {
      int sv = 0, dv = -1;
      if (l < 16 && (c0 + l) < K) { int2 pr = ovf[c0 + l]; dv = pr.x; sv = pr.y; }
      int myslot = l >> 2;
      int dmy = __shfl(dv, myslot, 64);
      int smy = __shfl(sv, myslot, 64);
      bool valid = (dmy == node);
      float z = -3.0e38f;
      if (valid) {
        float zz = a_src[(smy << 2) + hq] + adq;
        z = zz > 0.f ? zz : NEG_SLOPE * zz;
      }
      float cm = z;
      cm = fmaxf(cm, __shfl_xor(cm, 4, 64));
      cm = fmaxf(cm, __shfl_xor(cm, 8, 64));
      cm = fmaxf(cm, __shfl_xor(cm, 16, 64));
      cm = fmaxf(cm, __shfl_xor(cm, 32, 64));
      float m_new = fmaxf(m_run, cm);
      float resc_q = __expf(m_run - m_new);
      m_run = m_new;
      float wexp = valid ? __expf(z - m_new) : 0.f;
      swacc = swacc * resc_q + wexp;
      float resc_h = __shfl(resc_q, hg, 64);
#pragma unroll
      for (int k = 0; k < 8; k++) acc[k] *= resc_h;
#pragma unroll
      for (int js = 0; js < 4; js++) {
        int eidx = (js << 2) + q;
        float sw = __shfl(wexp, (eidx << 2) | hg, 64);
        int sj = __shfl(sv, eidx, 64);
        uint4 hv = *(const uint4*)(hfeat + (((size_t)sj) << 7) + (c8 << 3));
        unsigned uu[4] = {hv.x, hv.y, hv.z, hv.w};
#pragma unroll
        for (int k2 = 0; k2 < 4; k2++) {
          acc[2 * k2]     = fmaf(sw, bf2f((unsigned short)(uu[k2] & 0xffffu)), acc[2 * k2]);
          acc[2 * k2 + 1] = fmaf(sw, bf2f((unsigned short)(uu[k2] >> 16)), acc[2 * k2 + 1]);
        }
      }
    }
  }

  // per-head exp-sum over the 16 lanes sharing hq
  for (int m = 4; m < 64; m <<= 1) swacc += __shfl_xor(swacc, m, 64);
  // cross-quarter accumulator reduce
#pragma unroll
  for (int k = 0; k < 8; k++) {
    acc[k] += __shfl_xor(acc[k], 16, 64);
    acc[k] += __shfl_xor(acc[k], 32, 64);
  }
  float sumv = __shfl(swacc, hg, 64);
  float rs = 1.f / (sumv + EPSF);
  if (l < 16) {
    float o[8];
#pragma unroll
    for (int k = 0; k < 8; k++) o[k] = fmaf(acc[k], rs, bias_f[(c8 << 3) + k]);
    size_t base = (((size_t)node) << 7) + (c8 << 3);
    if (*flag) {
      *(float4*)((float*)outv + base)     = make_float4(o[0], o[1], o[2], o[3]);
      *(float4*)((float*)outv + base + 4) = make_float4(o[4], o[5], o[6], o[7]);
    } else {
      uint4 pk;
      pk.x = (unsigned)f2bf(o[0]) | ((unsigned)f2bf(o[1]) << 16);
      pk.y = (unsigned)f2bf(o[2]) | ((unsigned)f2bf(o[3]) << 16);
      pk.z = (unsigned)f2bf(o[4]) | ((unsigned)f2bf(o[5]) << 16);
      pk.w = (unsigned)f2bf(o[6]) | ((unsigned)f2bf(o[7]) << 16);
      *(uint4*)((unsigned short*)outv + base) = pk;
    }
  }
}

extern "C" void kernel_launch(void* const* d_in, const int* in_sizes, int n_in,
                              void* d_out, int out_size, void* d_ws, size_t ws_size,
                              hipStream_t stream) {
  const void* x    = d_in[0];
  const int*  ei   = (const int*)d_in[1];
  const void* w    = d_in[2];
  const void* att  = d_in[3];
  const void* bias = d_in[4];

  const int n = in_sizes[0] / 256;
  const int e = in_sizes[1] / 2;
  const int zb = (n + 255) / 256;            // cursor-zero blocks
  const int gb = (n + 127) / 128;            // gemm blocks
  const int fb = 2048;                       // fill blocks (multiple of 8)

  char* p = (char*)d_ws;
  size_t off = 0;
  auto carve = [&](size_t bytes) -> void* {
    void* r = p + off;
    off = (off + bytes + 255) & ~(size_t)255;
    return r;
  };
  int*      flag    = (int*)carve(sizeof(int));
  int*      ovf_cnt = (int*)carve(sizeof(int));
  float*    bias_f  = (float*)carve(128 * 4);
  unsigned short* h = (unsigned short*)carve((size_t)n * 128 * 2);   // 12.8 MB
  float*    a_src   = (float*)carve((size_t)n * 4 * 4);
  float*    a_dst   = (float*)carve((size_t)n * 4 * 4);
  int*      cursor  = (int*)carve((size_t)n * 4);
  int*      ed      = (int*)carve((size_t)n * 32 * 4);               // 6.4 MB
  int2*     ovf     = (int2*)carve((size_t)e * 8);                   // 6.4 MB
  unsigned short* bpack = (unsigned short*)carve((size_t)256 * 128 * 2);  // 64 KB
  unsigned short* wpack = (unsigned short*)carve((size_t)8 * 64 * 8 * 2); // 8 KB
  (void)ws_size;

  prep_k<<<zb + 145, 256, 0, stream>>>((const unsigned short*)x, w, att, bias,
                                       flag, cursor, ovf_cnt, bpack, wpack, bias_f,
                                       n, zb);
  gemmfill_k<<<gb + fb, 256, 0, stream>>>(x, flag, bpack, wpack, h, a_src, a_dst,
                                          ei, cursor, ed, ovf, ovf_cnt, n, e, gb, fb);
  agg_k<<<(n + 7) / 8, 512, 0, stream>>>(h, cursor, ed, ovf, ovf_cnt, a_src, a_dst,
                                         bias_f, flag, d_out, n, e);
}